// Round 5
// baseline (139.466 us; speedup 1.0000x reference)
//
#include <hip/hip_runtime.h>
#include <math.h>

#define PP 4096
#define CDIM 256
#define NHEADS 4
#define HD 64

typedef unsigned int u32t;
typedef unsigned short u16t;
typedef __attribute__((ext_vector_type(8))) short bf16x8;
typedef __attribute__((ext_vector_type(4))) float f32x4;

__device__ __forceinline__ float wave_sum(float v) {
#pragma unroll
  for (int off = 32; off > 0; off >>= 1) v += __shfl_down(v, off);
  return v;
}

__device__ __forceinline__ float bflo(u32t w) {
  return __uint_as_float(w << 16);
}
__device__ __forceinline__ float bfhi(u32t w) {
  return __uint_as_float(w & 0xffff0000u);
}
__device__ __forceinline__ u32t pack2(float lo, float hi) {
  const u32t a = __float_as_uint(lo), b = __float_as_uint(hi);
  const u32t l = (a + 0x7fffu + ((a >> 16) & 1u)) >> 16;
  const u32t h = (b + 0x7fffu + ((b >> 16) & 1u)) & 0xffff0000u;
  return l | h;
}

// ---- prep: pack x f32 [b][c][p] -> bf16 chunked [b][c32][p][8] + avg partials
__global__ __launch_bounds__(256) void k_prep(const float* __restrict__ x,
                                              u16t* __restrict__ xb,
                                              float* __restrict__ pavg) {
  const int p = blockIdx.x * 256 + threadIdx.x;
  const int c32 = blockIdx.y;  // 0..31
  const int b = blockIdx.z;
  const float* s = x + ((size_t)b * CDIM + c32 * 8) * PP + p;
  float f[8];
#pragma unroll
  for (int j = 0; j < 8; ++j) f[j] = s[(size_t)j * PP];
  u32t u[4];
#pragma unroll
  for (int jw = 0; jw < 4; ++jw) u[jw] = pack2(f[2 * jw], f[2 * jw + 1]);
  *(uint4*)&xb[(((size_t)b * 32 + c32) * PP + p) * 8] = *(const uint4*)u;
  // per-channel block sums for avg-pool
  __shared__ float red[4][8];
  const int lane = threadIdx.x & 63, wid = threadIdx.x >> 6;
#pragma unroll
  for (int j = 0; j < 8; ++j) {
    const float sj = wave_sum(f[j]);
    if (lane == 0) red[wid][j] = sj;
  }
  __syncthreads();
  if (threadIdx.x < 8) {
    const int j = threadIdx.x;
    pavg[(((size_t)b * 32 + c32) * 16 + blockIdx.x) * 8 + j] =
        red[0][j] + red[1][j] + red[2][j] + red[3][j];
  }
}

// ---- dirs: reduce avg partials -> linear -> normalize -> offsets ----
__global__ __launch_bounds__(256) void k_dirs(const float* __restrict__ pavg,
                                              const float* __restrict__ dirW,
                                              const float* __restrict__ dirb,
                                              float* __restrict__ offs) {
  __shared__ float avg_l[2][256];
  __shared__ float dv[2][32];
  const int c = threadIdx.x;
#pragma unroll
  for (int b = 0; b < 2; ++b) {
    float s = 0.f;
    for (int pb = 0; pb < 16; ++pb)
      s += pavg[(((size_t)b * 32 + (c >> 3)) * 16 + pb) * 8 + (c & 7)];
    avg_l[b][c] = s * (1.0f / PP);
  }
  __syncthreads();
  if (threadIdx.x < 64) {
    const int b = threadIdx.x >> 5, row = threadIdx.x & 31;
    const float* w = dirW + row * CDIM;
    float s = dirb[row];
    for (int cc = 0; cc < CDIM; ++cc) s = fmaf(avg_l[b][cc], w[cc], s);
    dv[b][row] = s;
  }
  __syncthreads();
  if (threadIdx.x < 32) {
    const int b = threadIdx.x >> 4, hs = threadIdx.x & 15;
    float vx = dv[b][hs * 2], vy = dv[b][hs * 2 + 1];
    const float n = fmaxf(sqrtf(vx * vx + vy * vy), 1e-6f);
    vx /= n;
    vy /= n;
#pragma unroll
    for (int m = 0; m < 8; ++m) {
      const float t = -0.5f + m * (1.0f / 7.0f);
      const int o = ((b * 16 + hs) * 8 + m) * 2;
      offs[o] = vx * t;
      offs[o + 1] = vy * t;
    }
  }
}

// ---- pack Wq/Wk/Wv f32 [o][c] -> bf16 A-layout [m][c32][o][8] ----
__global__ __launch_bounds__(256) void k_pack_w(const float* __restrict__ Wq,
                                                const float* __restrict__ Wk,
                                                const float* __restrict__ Wv,
                                                u16t* __restrict__ Wa) {
  const int c32 = blockIdx.x;  // 0..31
  const int m = blockIdx.y;    // 0..2
  const int o = threadIdx.x;   // 0..255
  const float* W = (m == 0 ? Wq : (m == 1 ? Wk : Wv));
  const float4 a = *(const float4*)&W[o * CDIM + c32 * 8];
  const float4 bq = *(const float4*)&W[o * CDIM + c32 * 8 + 4];
  u32t u[4];
  u[0] = pack2(a.x, a.y);
  u[1] = pack2(a.z, a.w);
  u[2] = pack2(bq.x, bq.y);
  u[3] = pack2(bq.z, bq.w);
  *(uint4*)&Wa[(((size_t)m * 32 + c32) * CDIM + o) * 8] = *(const uint4*)u;
}

// ---- fused QKV MFMA GEMM; coalesced chunk-uint4 epilogue via shfl ----
__global__ __launch_bounds__(256) void k_mfma_qkv(const u16t* __restrict__ Wa,
                                                  const u16t* __restrict__ xb,
                                                  u16t* __restrict__ Qc,
                                                  u16t* __restrict__ Kc,
                                                  u16t* __restrict__ Vc) {
  const int p0 = blockIdx.x * 64;
  const int ot = blockIdx.y;     // 0..11
  const int m = ot >> 2;         // 0=Q,1=K,2=V
  const int ob = (ot & 3) * 64;  // o base within matrix
  const int b = blockIdx.z;
  const int l = threadIdx.x & 63, w = threadIdx.x >> 6;
  const int lm = l & 15, lk = l >> 4;
  f32x4 acc[4] = {};
  const u16t* Ab = Wa + ((size_t)m * 32) * CDIM * 8 + (ob + w * 16 + lm) * 8;
  const u16t* Bb = xb + ((size_t)b * 32) * PP * 8 + ((size_t)p0 + lm) * 8;
  for (int c0 = 0; c0 < CDIM; c0 += 32) {
    const int ch = (c0 >> 3) + lk;
    const bf16x8 af = *(const bf16x8*)(Ab + (size_t)ch * CDIM * 8);
#pragma unroll
    for (int j = 0; j < 4; ++j) {
      const bf16x8 bf = *(const bf16x8*)(Bb + ((size_t)ch * PP + j * 16) * 8);
      acc[j] = __builtin_amdgcn_mfma_f32_16x16x32_bf16(af, bf, acc[j], 0, 0, 0);
    }
  }
  u16t* dst = (m == 0 ? Qc : (m == 1 ? Kc : Vc));
  // c32 chunk for this lane-pair; even-lk lanes store full 8-o uint4
  const int c32i = (ob >> 3) + w * 2 + (lk >> 1);
#pragma unroll
  for (int j = 0; j < 4; ++j) {
    const u32t lo = pack2(acc[j][0], acc[j][1]);
    const u32t hi = pack2(acc[j][2], acc[j][3]);
    const u32t plo = __shfl_xor(lo, 16);
    const u32t phi = __shfl_xor(hi, 16);
    if ((l & 16) == 0) {
      uint4 v;
      v.x = lo;
      v.y = hi;
      v.z = plo;
      v.w = phi;
      *(uint4*)&dst[(((size_t)b * 32 + c32i) * PP + p0 + j * 16 + lm) * 8] = v;
    }
  }
}

// ---------------- bilinear sample setup ----------------
struct Samp {
  int i00, i01, i10, i11;
  float w00, w01, w10, w11;
};
__device__ __forceinline__ Samp samp(int xi, int yi, float dxn, float dyn) {
  float gx = fminf(fmaxf(-1.0f + xi * (2.0f / 63.0f) + dxn, -1.0f), 1.0f);
  float gy = fminf(fmaxf(-1.0f + yi * (2.0f / 63.0f) + dyn, -1.0f), 1.0f);
  const float px = (gx + 1.0f) * 31.5f;
  const float py = (gy + 1.0f) * 31.5f;
  const float x0f = floorf(px), y0f = floorf(py);
  const float fx = px - x0f, fy = py - y0f;
  int x0 = (int)x0f;
  x0 = x0 < 0 ? 0 : (x0 > 63 ? 63 : x0);
  int y0 = (int)y0f;
  y0 = y0 < 0 ? 0 : (y0 > 63 ? 63 : y0);
  const int x1 = x0 + 1 > 63 ? 63 : x0 + 1;
  const int y1 = y0 + 1 > 63 ? 63 : y0 + 1;
  Samp sp;
  sp.i00 = y0 * 64 + x0;
  sp.i01 = y0 * 64 + x1;
  sp.i10 = y1 * 64 + x0;
  sp.i11 = y1 * 64 + x1;
  const float ifx = 1.0f - fx, ify = 1.0f - fy;
  sp.w00 = ifx * ify;
  sp.w01 = fx * ify;
  sp.w10 = ifx * fy;
  sp.w11 = fx * fy;
  return sp;
}

__device__ __forceinline__ float dot8(const float* q, uint4 v) {
  float a = q[0] * bflo(v.x);
  a = fmaf(q[1], bfhi(v.x), a);
  a = fmaf(q[2], bflo(v.y), a);
  a = fmaf(q[3], bfhi(v.y), a);
  a = fmaf(q[4], bflo(v.z), a);
  a = fmaf(q[5], bfhi(v.z), a);
  a = fmaf(q[6], bflo(v.w), a);
  a = fmaf(q[7], bfhi(v.w), a);
  return a;
}

// ---- logits: thread per (p, strip); writes p-major lg[bh][p][32] ----
__global__ __launch_bounds__(256) void k_logits(const uint4* __restrict__ Qc,
                                                const uint4* __restrict__ Kc,
                                                const float* __restrict__ offs,
                                                float* __restrict__ lg) {
  const int p = blockIdx.x * 256 + threadIdx.x;
  const int s = blockIdx.y;   // strip 0..3
  const int bh = blockIdx.z;  // 0..7
  const int b = bh >> 2, h = bh & 3;
  float q[64];
  {
    const uint4* Qp = Qc + ((size_t)b * 32 + h * 8) * PP + p;
#pragma unroll
    for (int c8 = 0; c8 < 8; ++c8) {
      const uint4 v = Qp[(size_t)c8 * PP];
      q[c8 * 8 + 0] = bflo(v.x);
      q[c8 * 8 + 1] = bfhi(v.x);
      q[c8 * 8 + 2] = bflo(v.y);
      q[c8 * 8 + 3] = bfhi(v.y);
      q[c8 * 8 + 4] = bflo(v.z);
      q[c8 * 8 + 5] = bfhi(v.z);
      q[c8 * 8 + 6] = bflo(v.w);
      q[c8 * 8 + 7] = bfhi(v.w);
    }
  }
  const int xi = p & 63, yi = p >> 6;
  float* lgp = lg + ((size_t)bh * PP + p) * 32 + s * 8;
  for (int m = 0; m < 8; ++m) {
    const int obase = ((b * 16 + h * 4 + s) * 8 + m) * 2;
    const Samp sp = samp(xi, yi, offs[obase], offs[obase + 1]);
    float a00 = 0.f, a01 = 0.f, a10 = 0.f, a11 = 0.f;
#pragma unroll
    for (int c8 = 0; c8 < 8; ++c8) {
      const uint4* Kb8 = Kc + ((size_t)b * 32 + h * 8 + c8) * PP;
      const uint4 v00 = Kb8[sp.i00];
      const uint4 v01 = Kb8[sp.i01];
      const uint4 v10 = Kb8[sp.i10];
      const uint4 v11 = Kb8[sp.i11];
      const float* qq = q + c8 * 8;
      a00 += dot8(qq, v00);
      a01 += dot8(qq, v01);
      a10 += dot8(qq, v10);
      a11 += dot8(qq, v11);
    }
    lgp[m] =
        (sp.w00 * a00 + sp.w01 * a01 + sp.w10 * a10 + sp.w11 * a11) * 0.125f;
  }
}

// ---- softmax once per p: lg f32 [bh][p][32] -> wb bf16 [bh][p][32] ----
__global__ __launch_bounds__(256) void k_softmax(const float* __restrict__ lg,
                                                 u16t* __restrict__ wb) {
  const size_t idx = (size_t)blockIdx.x * 256 + threadIdx.x;  // bh*4096+p
  const float4* b4 = (const float4*)(lg + idx * 32);
  float v[32];
#pragma unroll
  for (int i = 0; i < 8; ++i) {
    const float4 t = b4[i];
    v[i * 4 + 0] = t.x;
    v[i * 4 + 1] = t.y;
    v[i * 4 + 2] = t.z;
    v[i * 4 + 3] = t.w;
  }
  float mx = -1e30f;
#pragma unroll
  for (int k = 0; k < 32; ++k) mx = fmaxf(mx, v[k]);
  float sum = 0.f;
#pragma unroll
  for (int k = 0; k < 32; ++k) {
    v[k] = __expf(v[k] - mx);
    sum += v[k];
  }
  const float inv = 1.0f / sum;
  u32t u[16];
#pragma unroll
  for (int i = 0; i < 16; ++i)
    u[i] = pack2(v[2 * i] * inv, v[2 * i + 1] * inv);
  uint4* dst = (uint4*)(wb + idx * 32);
#pragma unroll
  for (int i = 0; i < 4; ++i) dst[i] = *(const uint4*)&u[i * 4];
}

__device__ __forceinline__ void acc8(float* a, uint4 v, float w) {
  a[0] = fmaf(w, bflo(v.x), a[0]);
  a[1] = fmaf(w, bfhi(v.x), a[1]);
  a[2] = fmaf(w, bflo(v.y), a[2]);
  a[3] = fmaf(w, bfhi(v.y), a[3]);
  a[4] = fmaf(w, bflo(v.z), a[4]);
  a[5] = fmaf(w, bfhi(v.z), a[5]);
  a[6] = fmaf(w, bflo(v.w), a[6]);
  a[7] = fmaf(w, bfhi(v.w), a[7]);
}

// ---- PV: weights from wb; writes bf16 Obc + GN partials ----
__global__ __launch_bounds__(256) void k_pv(const uint4* __restrict__ Vc,
                                            const u16t* __restrict__ wb,
                                            const float* __restrict__ offs,
                                            u16t* __restrict__ Obc,
                                            float* __restrict__ part) {
  const int p = blockIdx.x * 256 + threadIdx.x;
  const int g = blockIdx.y;   // 0..3 -> d range g*16..g*16+15
  const int bh = blockIdx.z;  // 0..7
  const int b = bh >> 2, h = bh & 3;
  const u16t* wrow = wb + ((size_t)bh * PP + p) * 32;
  const int xi = p & 63, yi = p >> 6;
  float acc[16] = {};
  for (int k = 0; k < 32; ++k) {
    const int obase = ((b * 16 + h * 4 + (k >> 3)) * 8 + (k & 7)) * 2;
    const Samp sp = samp(xi, yi, offs[obase], offs[obase + 1]);
    const float ww = __uint_as_float(((u32t)wrow[k]) << 16);
    const float w00 = ww * sp.w00, w01 = ww * sp.w01;
    const float w10 = ww * sp.w10, w11 = ww * sp.w11;
#pragma unroll
    for (int cc = 0; cc < 2; ++cc) {
      const uint4* Vb8 = Vc + ((size_t)b * 32 + h * 8 + 2 * g + cc) * PP;
      const uint4 v00 = Vb8[sp.i00];
      const uint4 v01 = Vb8[sp.i01];
      const uint4 v10 = Vb8[sp.i10];
      const uint4 v11 = Vb8[sp.i11];
      float* a = acc + cc * 8;
      acc8(a, v00, w00);
      acc8(a, v01, w01);
      acc8(a, v10, w10);
      acc8(a, v11, w11);
    }
  }
#pragma unroll
  for (int cc = 0; cc < 2; ++cc) {
    const int c32 = h * 8 + g * 2 + cc;
    u32t u[4];
#pragma unroll
    for (int jw = 0; jw < 4; ++jw)
      u[jw] = pack2(acc[cc * 8 + 2 * jw], acc[cc * 8 + 2 * jw + 1]);
    *(uint4*)&Obc[(((size_t)b * 32 + c32) * PP + p) * 8] = *(const uint4*)u;
  }
  // GN partials over this block's 256 p x 16 d
  float s1 = 0.f, s2 = 0.f;
#pragma unroll
  for (int d = 0; d < 16; ++d) {
    s1 += acc[d];
    s2 += acc[d] * acc[d];
  }
  __shared__ float r1[4], r2[4];
  s1 = wave_sum(s1);
  s2 = wave_sum(s2);
  const int lane = threadIdx.x & 63, wid = threadIdx.x >> 6;
  if (lane == 0) {
    r1[wid] = s1;
    r2[wid] = s2;
  }
  __syncthreads();
  if (threadIdx.x == 0) {
    const size_t slot = (size_t)bh * 64 + blockIdx.x * 4 + g;
    part[slot * 2] = r1[0] + r1[1] + r1[2] + r1[3];
    part[slot * 2 + 1] = r2[0] + r2[1] + r2[2] + r2[3];
  }
}

// ---- finalize: stats from partials + pack Wo' + per-(b,o) bias ----
__global__ __launch_bounds__(256) void k_finalprep(
    const float* __restrict__ part, const float* __restrict__ Wo,
    const float* __restrict__ bo, const float* __restrict__ gnw,
    const float* __restrict__ gnb, u16t* __restrict__ Woa,
    float* __restrict__ obias) {
  const int b = blockIdx.x;
  __shared__ float mu_l[4], rs_l[4];
  {
    const int g = threadIdx.x >> 6, slot = threadIdx.x & 63;
    const size_t base = (((size_t)b * 4 + g) * 64 + slot) * 2;
    float s1 = part[base];
    float s2 = part[base + 1];
    s1 = wave_sum(s1);
    s2 = wave_sum(s2);
    if (slot == 0) {
      const float inv = 1.0f / (HD * PP);
      const float mu = s1 * inv;
      const float var = s2 * inv - mu * mu;
      mu_l[g] = mu;
      rs_l[g] = rsqrtf(var + 1e-5f);
    }
  }
  __syncthreads();
  const int o = threadIdx.x;
  float acc = bo[o];
  for (int c = 0; c < CDIM; ++c) {
    const int g = c >> 6;
    acc = fmaf(Wo[o * CDIM + c], gnb[c] - mu_l[g] * rs_l[g] * gnw[c], acc);
  }
  obias[b * CDIM + o] = acc;
  for (int c32 = 0; c32 < 32; ++c32) {
    const float rs = rs_l[c32 >> 3];
    float wv[8];
#pragma unroll
    for (int j = 0; j < 8; ++j) {
      const int c = c32 * 8 + j;
      wv[j] = Wo[o * CDIM + c] * rs * gnw[c];
    }
    u32t u[4];
#pragma unroll
    for (int jw = 0; jw < 4; ++jw) u[jw] = pack2(wv[2 * jw], wv[2 * jw + 1]);
    *(uint4*)&Woa[(((size_t)b * 32 + c32) * CDIM + o) * 8] = *(const uint4*)u;
  }
}

// ---- final MFMA GEMM: out = Wo' @ Obc + obias + x ----
__global__ __launch_bounds__(256) void k_mfma_out(
    const u16t* __restrict__ Woa, const u16t* __restrict__ Obc,
    const float* __restrict__ obias, const float* __restrict__ x,
    float* __restrict__ outp) {
  const int p0 = blockIdx.x * 64;
  const int ob = blockIdx.y * 64;
  const int b = blockIdx.z;
  const int l = threadIdx.x & 63, w = threadIdx.x >> 6;
  const int lm = l & 15, lk = l >> 4;
  f32x4 acc[4] = {};
  const u16t* Ab = Woa + ((size_t)b * 32) * CDIM * 8 + (ob + w * 16 + lm) * 8;
  const u16t* Bb = Obc + ((size_t)b * 32) * PP * 8 + ((size_t)p0 + lm) * 8;
  for (int c0 = 0; c0 < CDIM; c0 += 32) {
    const int ch = (c0 >> 3) + lk;
    const bf16x8 af = *(const bf16x8*)(Ab + (size_t)ch * CDIM * 8);
#pragma unroll
    for (int j = 0; j < 4; ++j) {
      const bf16x8 bf = *(const bf16x8*)(Bb + ((size_t)ch * PP + j * 16) * 8);
      acc[j] = __builtin_amdgcn_mfma_f32_16x16x32_bf16(af, bf, acc[j], 0, 0, 0);
    }
  }
#pragma unroll
  for (int j = 0; j < 4; ++j) {
    const int p = p0 + j * 16 + lm;
#pragma unroll
    for (int r = 0; r < 4; ++r) {
      const int o = ob + w * 16 + lk * 4 + r;
      const size_t idx = ((size_t)b * CDIM + o) * PP + p;
      outp[idx] = acc[j][r] + obias[b * CDIM + o] + x[idx];
    }
  }
}

extern "C" void kernel_launch(void* const* d_in, const int* in_sizes, int n_in,
                              void* d_out, int out_size, void* d_ws,
                              size_t ws_size, hipStream_t stream) {
  const float* x = (const float*)d_in[0];
  const float* Wq = (const float*)d_in[1];
  const float* Wk = (const float*)d_in[2];
  const float* Wv = (const float*)d_in[3];
  const float* Wo = (const float*)d_in[4];
  const float* bo = (const float*)d_in[5];
  const float* dirW = (const float*)d_in[6];
  const float* dirb = (const float*)d_in[7];
  const float* gnw = (const float*)d_in[8];
  const float* gnb = (const float*)d_in[9];
  float* outp = (float*)d_out;

  float* ws = (float*)d_ws;
  float* offs = ws + 512;     // 1024 floats
  float* pavg = ws + 2048;    // 8192
  float* part = ws + 10240;   // 1024
  float* obias = ws + 11264;  // 512
  u16t* xb = (u16t*)(ws + 16384);      // 2,097,152 u16 -> ends f32 1,064,960
  u16t* Wa = (u16t*)(ws + 1064960);    // 196,608 u16 -> ends 1,163,264
  u16t* Woa = (u16t*)(ws + 1163264);   // 131,072 u16 -> ends 1,228,800
  u16t* Qc = (u16t*)(ws + 1228800);    // 2,097,152 u16 -> ends 2,277,376
  u16t* Kc = (u16t*)(ws + 2277376);    // -> ends 3,325,952
  u16t* Vc = (u16t*)(ws + 3325952);    // -> ends 4,374,528
  float* lg = ws + 4374528;            // f32 [8][4096][32] -> ends 5,423,104
  u16t* wb = (u16t*)(ws + 5423104);    // bf16 [8][4096][32] -> ends 5,947,392
  u16t* Obc = (u16t*)lg;               // aliases lg (dead after softmax)

  k_prep<<<dim3(16, 32, 2), dim3(256), 0, stream>>>(x, xb, pavg);
  k_dirs<<<dim3(1), dim3(256), 0, stream>>>(pavg, dirW, dirb, offs);
  k_pack_w<<<dim3(32, 3), dim3(256), 0, stream>>>(Wq, Wk, Wv, Wa);
  k_mfma_qkv<<<dim3(64, 12, 2), dim3(256), 0, stream>>>(Wa, xb, Qc, Kc, Vc);
  k_logits<<<dim3(16, 4, 8), dim3(256), 0, stream>>>(
      (const uint4*)Qc, (const uint4*)Kc, offs, lg);
  k_softmax<<<dim3(128), dim3(256), 0, stream>>>(lg, wb);
  k_pv<<<dim3(16, 4, 8), dim3(256), 0, stream>>>((const uint4*)Vc, wb, offs,
                                                 Obc, part);
  k_finalprep<<<dim3(2), dim3(256), 0, stream>>>(part, Wo, bo, gnw, gnb, Woa,
                                                 obias);
  k_mfma_out<<<dim3(64, 4, 2), dim3(256), 0, stream>>>(Woa, Obc, obias, x,
                                                       outp);
}

// Round 6
// 101.544 us; speedup vs baseline: 1.3735x; 1.3735x over previous
//
#include <hip/hip_runtime.h>
#include <math.h>

#define PP 4096
#define CDIM 256
#define NHEADS 4
#define HD 64

typedef unsigned int u32t;
typedef unsigned short u16t;
typedef __attribute__((ext_vector_type(8))) short bf16x8;
typedef __attribute__((ext_vector_type(4))) float f32x4;

__device__ __forceinline__ float wave_sum(float v) {
#pragma unroll
  for (int off = 32; off > 0; off >>= 1) v += __shfl_down(v, off);
  return v;
}

__device__ __forceinline__ float bflo(u32t w) {
  return __uint_as_float(w << 16);
}
__device__ __forceinline__ float bfhi(u32t w) {
  return __uint_as_float(w & 0xffff0000u);
}
__device__ __forceinline__ u32t pack2(float lo, float hi) {
  const u32t a = __float_as_uint(lo), b = __float_as_uint(hi);
  const u32t l = (a + 0x7fffu + ((a >> 16) & 1u)) >> 16;
  const u32t h = (b + 0x7fffu + ((b >> 16) & 1u)) & 0xffff0000u;
  return l | h;
}
__device__ __forceinline__ u16t f2bf(float f) {
  u32t u = __float_as_uint(f);
  u = u + 0x7fffu + ((u >> 16) & 1u);
  return (u16t)(u >> 16);
}

// ---- prep: pack x f32 [b][c][p] -> bf16 chunked [b][c32][p][8] + avg partials
__global__ __launch_bounds__(256) void k_prep(const float* __restrict__ x,
                                              u16t* __restrict__ xb,
                                              float* __restrict__ pavg) {
  const int p = blockIdx.x * 256 + threadIdx.x;
  const int c32 = blockIdx.y;  // 0..31
  const int b = blockIdx.z;
  const float* s = x + ((size_t)b * CDIM + c32 * 8) * PP + p;
  float f[8];
#pragma unroll
  for (int j = 0; j < 8; ++j) f[j] = s[(size_t)j * PP];
  u32t u[4];
#pragma unroll
  for (int jw = 0; jw < 4; ++jw) u[jw] = pack2(f[2 * jw], f[2 * jw + 1]);
  *(uint4*)&xb[(((size_t)b * 32 + c32) * PP + p) * 8] = *(const uint4*)u;
  __shared__ float red[4][8];
  const int lane = threadIdx.x & 63, wid = threadIdx.x >> 6;
#pragma unroll
  for (int j = 0; j < 8; ++j) {
    const float sj = wave_sum(f[j]);
    if (lane == 0) red[wid][j] = sj;
  }
  __syncthreads();
  if (threadIdx.x < 8) {
    const int j = threadIdx.x;
    pavg[(((size_t)b * 32 + c32) * 16 + blockIdx.x) * 8 + j] =
        red[0][j] + red[1][j] + red[2][j] + red[3][j];
  }
}

// ---- dirs: reduce avg partials -> linear -> normalize -> offsets ----
__global__ __launch_bounds__(256) void k_dirs(const float* __restrict__ pavg,
                                              const float* __restrict__ dirW,
                                              const float* __restrict__ dirb,
                                              float* __restrict__ offs) {
  __shared__ float avg_l[2][256];
  __shared__ float dv[2][32];
  const int c = threadIdx.x;
#pragma unroll
  for (int b = 0; b < 2; ++b) {
    float s = 0.f;
    for (int pb = 0; pb < 16; ++pb)
      s += pavg[(((size_t)b * 32 + (c >> 3)) * 16 + pb) * 8 + (c & 7)];
    avg_l[b][c] = s * (1.0f / PP);
  }
  __syncthreads();
  if (threadIdx.x < 64) {
    const int b = threadIdx.x >> 5, row = threadIdx.x & 31;
    const float* w = dirW + row * CDIM;
    float s = dirb[row];
    for (int cc = 0; cc < CDIM; ++cc) s = fmaf(avg_l[b][cc], w[cc], s);
    dv[b][row] = s;
  }
  __syncthreads();
  if (threadIdx.x < 32) {
    const int b = threadIdx.x >> 4, hs = threadIdx.x & 15;
    float vx = dv[b][hs * 2], vy = dv[b][hs * 2 + 1];
    const float n = fmaxf(sqrtf(vx * vx + vy * vy), 1e-6f);
    vx /= n;
    vy /= n;
#pragma unroll
    for (int m = 0; m < 8; ++m) {
      const float t = -0.5f + m * (1.0f / 7.0f);
      const int o = ((b * 16 + hs) * 8 + m) * 2;
      offs[o] = vx * t;
      offs[o + 1] = vy * t;
    }
  }
}

// ---- pack Wq/Wk/Wv f32 [o][c] -> bf16 A-layout [m][c32][o][8] ----
__global__ __launch_bounds__(256) void k_pack_w(const float* __restrict__ Wq,
                                                const float* __restrict__ Wk,
                                                const float* __restrict__ Wv,
                                                u16t* __restrict__ Wa) {
  const int c32 = blockIdx.x;  // 0..31
  const int m = blockIdx.y;    // 0..2
  const int o = threadIdx.x;   // 0..255
  const float* W = (m == 0 ? Wq : (m == 1 ? Wk : Wv));
  const float4 a = *(const float4*)&W[o * CDIM + c32 * 8];
  const float4 bq = *(const float4*)&W[o * CDIM + c32 * 8 + 4];
  u32t u[4];
  u[0] = pack2(a.x, a.y);
  u[1] = pack2(a.z, a.w);
  u[2] = pack2(bq.x, bq.y);
  u[3] = pack2(bq.z, bq.w);
  *(uint4*)&Wa[(((size_t)m * 32 + c32) * CDIM + o) * 8] = *(const uint4*)u;
}

// ---- wprep (stats-INDEPENDENT, off critical path): per output row o,
//      Wog pack (Wo*gnw, bf16 A-layout [c32][o][8]),
//      Rg[o][g] = sum_{c in g} Wo[o][c]*gnw[c],
//      Cg[o]    = bo[o] + sum_c Wo[o][c]*gnb[c]
__global__ __launch_bounds__(256) void k_wprep(const float* __restrict__ Wo,
                                               const float* __restrict__ bo,
                                               const float* __restrict__ gnw,
                                               const float* __restrict__ gnb,
                                               u16t* __restrict__ Wog,
                                               float* __restrict__ Rg,
                                               float* __restrict__ Cg) {
  const int o = blockIdx.x;   // 0..255
  const int c = threadIdx.x;  // 0..255 ; wave = GN group
  const float wv = Wo[o * CDIM + c];
  const float wg = wv * gnw[c];
  Wog[(((size_t)(c >> 3)) * CDIM + o) * 8 + (c & 7)] = f2bf(wg);
  const float rsum = wave_sum(wg);
  const float csum = wave_sum(wv * gnb[c]);
  __shared__ float redc[4];
  const int lane = c & 63, g = c >> 6;
  if (lane == 0) {
    Rg[o * 4 + g] = rsum;
    redc[g] = csum;
  }
  __syncthreads();
  if (threadIdx.x == 0)
    Cg[o] = bo[o] + redc[0] + redc[1] + redc[2] + redc[3];
}

// ---- fused QKV MFMA GEMM; coalesced chunk-uint4 epilogue via shfl ----
__global__ __launch_bounds__(256) void k_mfma_qkv(const u16t* __restrict__ Wa,
                                                  const u16t* __restrict__ xb,
                                                  u16t* __restrict__ Qc,
                                                  u16t* __restrict__ Kc,
                                                  u16t* __restrict__ Vc) {
  const int p0 = blockIdx.x * 64;
  const int ot = blockIdx.y;     // 0..11
  const int m = ot >> 2;         // 0=Q,1=K,2=V
  const int ob = (ot & 3) * 64;  // o base within matrix
  const int b = blockIdx.z;
  const int l = threadIdx.x & 63, w = threadIdx.x >> 6;
  const int lm = l & 15, lk = l >> 4;
  f32x4 acc[4] = {};
  const u16t* Ab = Wa + ((size_t)m * 32) * CDIM * 8 + (ob + w * 16 + lm) * 8;
  const u16t* Bb = xb + ((size_t)b * 32) * PP * 8 + ((size_t)p0 + lm) * 8;
  for (int c0 = 0; c0 < CDIM; c0 += 32) {
    const int ch = (c0 >> 3) + lk;
    const bf16x8 af = *(const bf16x8*)(Ab + (size_t)ch * CDIM * 8);
#pragma unroll
    for (int j = 0; j < 4; ++j) {
      const bf16x8 bf = *(const bf16x8*)(Bb + ((size_t)ch * PP + j * 16) * 8);
      acc[j] = __builtin_amdgcn_mfma_f32_16x16x32_bf16(af, bf, acc[j], 0, 0, 0);
    }
  }
  u16t* dst = (m == 0 ? Qc : (m == 1 ? Kc : Vc));
  const int c32i = (ob >> 3) + w * 2 + (lk >> 1);
#pragma unroll
  for (int j = 0; j < 4; ++j) {
    const u32t lo = pack2(acc[j][0], acc[j][1]);
    const u32t hi = pack2(acc[j][2], acc[j][3]);
    const u32t plo = __shfl_xor(lo, 16);
    const u32t phi = __shfl_xor(hi, 16);
    if ((l & 16) == 0) {
      uint4 v;
      v.x = lo;
      v.y = hi;
      v.z = plo;
      v.w = phi;
      *(uint4*)&dst[(((size_t)b * 32 + c32i) * PP + p0 + j * 16 + lm) * 8] = v;
    }
  }
}

// ---------------- bilinear sample setup ----------------
struct Samp {
  int i00, i01, i10, i11;
  float w00, w01, w10, w11;
};
__device__ __forceinline__ Samp samp(int xi, int yi, float dxn, float dyn) {
  float gx = fminf(fmaxf(-1.0f + xi * (2.0f / 63.0f) + dxn, -1.0f), 1.0f);
  float gy = fminf(fmaxf(-1.0f + yi * (2.0f / 63.0f) + dyn, -1.0f), 1.0f);
  const float px = (gx + 1.0f) * 31.5f;
  const float py = (gy + 1.0f) * 31.5f;
  const float x0f = floorf(px), y0f = floorf(py);
  const float fx = px - x0f, fy = py - y0f;
  int x0 = (int)x0f;
  x0 = x0 < 0 ? 0 : (x0 > 63 ? 63 : x0);
  int y0 = (int)y0f;
  y0 = y0 < 0 ? 0 : (y0 > 63 ? 63 : y0);
  const int x1 = x0 + 1 > 63 ? 63 : x0 + 1;
  const int y1 = y0 + 1 > 63 ? 63 : y0 + 1;
  Samp sp;
  sp.i00 = y0 * 64 + x0;
  sp.i01 = y0 * 64 + x1;
  sp.i10 = y1 * 64 + x0;
  sp.i11 = y1 * 64 + x1;
  const float ifx = 1.0f - fx, ify = 1.0f - fy;
  sp.w00 = ifx * ify;
  sp.w01 = fx * ify;
  sp.w10 = ifx * fy;
  sp.w11 = fx * fy;
  return sp;
}

__device__ __forceinline__ float dot8(const float* q, uint4 v) {
  float a = q[0] * bflo(v.x);
  a = fmaf(q[1], bfhi(v.x), a);
  a = fmaf(q[2], bflo(v.y), a);
  a = fmaf(q[3], bfhi(v.y), a);
  a = fmaf(q[4], bflo(v.z), a);
  a = fmaf(q[5], bfhi(v.z), a);
  a = fmaf(q[6], bflo(v.w), a);
  a = fmaf(q[7], bfhi(v.w), a);
  return a;
}

// ---- logits: thread per (p, strip); writes p-major lg[bh][p][32] ----
__global__ __launch_bounds__(256) void k_logits(const uint4* __restrict__ Qc,
                                                const uint4* __restrict__ Kc,
                                                const float* __restrict__ offs,
                                                float* __restrict__ lg) {
  const int p = blockIdx.x * 256 + threadIdx.x;
  const int s = blockIdx.y;   // strip 0..3
  const int bh = blockIdx.z;  // 0..7
  const int b = bh >> 2, h = bh & 3;
  float q[64];
  {
    const uint4* Qp = Qc + ((size_t)b * 32 + h * 8) * PP + p;
#pragma unroll
    for (int c8 = 0; c8 < 8; ++c8) {
      const uint4 v = Qp[(size_t)c8 * PP];
      q[c8 * 8 + 0] = bflo(v.x);
      q[c8 * 8 + 1] = bfhi(v.x);
      q[c8 * 8 + 2] = bflo(v.y);
      q[c8 * 8 + 3] = bfhi(v.y);
      q[c8 * 8 + 4] = bflo(v.z);
      q[c8 * 8 + 5] = bfhi(v.z);
      q[c8 * 8 + 6] = bflo(v.w);
      q[c8 * 8 + 7] = bfhi(v.w);
    }
  }
  const int xi = p & 63, yi = p >> 6;
  float* lgp = lg + ((size_t)bh * PP + p) * 32 + s * 8;
  for (int m = 0; m < 8; ++m) {
    const int obase = ((b * 16 + h * 4 + s) * 8 + m) * 2;
    const Samp sp = samp(xi, yi, offs[obase], offs[obase + 1]);
    float a00 = 0.f, a01 = 0.f, a10 = 0.f, a11 = 0.f;
#pragma unroll
    for (int c8 = 0; c8 < 8; ++c8) {
      const uint4* Kb8 = Kc + ((size_t)b * 32 + h * 8 + c8) * PP;
      const uint4 v00 = Kb8[sp.i00];
      const uint4 v01 = Kb8[sp.i01];
      const uint4 v10 = Kb8[sp.i10];
      const uint4 v11 = Kb8[sp.i11];
      const float* qq = q + c8 * 8;
      a00 += dot8(qq, v00);
      a01 += dot8(qq, v01);
      a10 += dot8(qq, v10);
      a11 += dot8(qq, v11);
    }
    lgp[m] =
        (sp.w00 * a00 + sp.w01 * a01 + sp.w10 * a10 + sp.w11 * a11) * 0.125f;
  }
}

// ---- softmax once per p: lg f32 [bh][p][32] -> wb bf16 [bh][p][32] ----
__global__ __launch_bounds__(256) void k_softmax(const float* __restrict__ lg,
                                                 u16t* __restrict__ wb) {
  const size_t idx = (size_t)blockIdx.x * 256 + threadIdx.x;  // bh*4096+p
  const float4* b4 = (const float4*)(lg + idx * 32);
  float v[32];
#pragma unroll
  for (int i = 0; i < 8; ++i) {
    const float4 t = b4[i];
    v[i * 4 + 0] = t.x;
    v[i * 4 + 1] = t.y;
    v[i * 4 + 2] = t.z;
    v[i * 4 + 3] = t.w;
  }
  float mx = -1e30f;
#pragma unroll
  for (int k = 0; k < 32; ++k) mx = fmaxf(mx, v[k]);
  float sum = 0.f;
#pragma unroll
  for (int k = 0; k < 32; ++k) {
    v[k] = __expf(v[k] - mx);
    sum += v[k];
  }
  const float inv = 1.0f / sum;
  u32t u[16];
#pragma unroll
  for (int i = 0; i < 16; ++i) u[i] = pack2(v[2 * i] * inv, v[2 * i + 1] * inv);
  uint4* dst = (uint4*)(wb + idx * 32);
#pragma unroll
  for (int i = 0; i < 4; ++i) dst[i] = *(const uint4*)&u[i * 4];
}

__device__ __forceinline__ void acc8(float* a, uint4 v, float w) {
  a[0] = fmaf(w, bflo(v.x), a[0]);
  a[1] = fmaf(w, bfhi(v.x), a[1]);
  a[2] = fmaf(w, bflo(v.y), a[2]);
  a[3] = fmaf(w, bfhi(v.y), a[3]);
  a[4] = fmaf(w, bflo(v.z), a[4]);
  a[5] = fmaf(w, bfhi(v.z), a[5]);
  a[6] = fmaf(w, bflo(v.w), a[6]);
  a[7] = fmaf(w, bfhi(v.w), a[7]);
}

// ---- PV: weights from wb; writes bf16 Obc + GN partials ----
__global__ __launch_bounds__(256) void k_pv(const uint4* __restrict__ Vc,
                                            const u16t* __restrict__ wb,
                                            const float* __restrict__ offs,
                                            u16t* __restrict__ Obc,
                                            float* __restrict__ part) {
  const int p = blockIdx.x * 256 + threadIdx.x;
  const int g = blockIdx.y;   // 0..3 -> d range g*16..g*16+15
  const int bh = blockIdx.z;  // 0..7
  const int b = bh >> 2, h = bh & 3;
  const u16t* wrow = wb + ((size_t)bh * PP + p) * 32;
  const int xi = p & 63, yi = p >> 6;
  float acc[16] = {};
  for (int k = 0; k < 32; ++k) {
    const int obase = ((b * 16 + h * 4 + (k >> 3)) * 8 + (k & 7)) * 2;
    const Samp sp = samp(xi, yi, offs[obase], offs[obase + 1]);
    const float ww = __uint_as_float(((u32t)wrow[k]) << 16);
    const float w00 = ww * sp.w00, w01 = ww * sp.w01;
    const float w10 = ww * sp.w10, w11 = ww * sp.w11;
#pragma unroll
    for (int cc = 0; cc < 2; ++cc) {
      const uint4* Vb8 = Vc + ((size_t)b * 32 + h * 8 + 2 * g + cc) * PP;
      const uint4 v00 = Vb8[sp.i00];
      const uint4 v01 = Vb8[sp.i01];
      const uint4 v10 = Vb8[sp.i10];
      const uint4 v11 = Vb8[sp.i11];
      float* a = acc + cc * 8;
      acc8(a, v00, w00);
      acc8(a, v01, w01);
      acc8(a, v10, w10);
      acc8(a, v11, w11);
    }
  }
#pragma unroll
  for (int cc = 0; cc < 2; ++cc) {
    const int c32 = h * 8 + g * 2 + cc;
    u32t u[4];
#pragma unroll
    for (int jw = 0; jw < 4; ++jw)
      u[jw] = pack2(acc[cc * 8 + 2 * jw], acc[cc * 8 + 2 * jw + 1]);
    *(uint4*)&Obc[(((size_t)b * 32 + c32) * PP + p) * 8] = *(const uint4*)u;
  }
  float s1 = 0.f, s2 = 0.f;
#pragma unroll
  for (int d = 0; d < 16; ++d) {
    s1 += acc[d];
    s2 += acc[d] * acc[d];
  }
  __shared__ float r1[4], r2[4];
  s1 = wave_sum(s1);
  s2 = wave_sum(s2);
  const int lane = threadIdx.x & 63, wid = threadIdx.x >> 6;
  if (lane == 0) {
    r1[wid] = s1;
    r2[wid] = s2;
  }
  __syncthreads();
  if (threadIdx.x == 0) {
    const size_t slot = (size_t)bh * 64 + blockIdx.x * 4 + g;
    part[slot * 2] = r1[0] + r1[1] + r1[2] + r1[3];
    part[slot * 2 + 1] = r2[0] + r2[1] + r2[2] + r2[3];
  }
}

// ---- finalstats: 1 block, wave w reduces group w's 64 partial slots ----
__global__ __launch_bounds__(512) void k_finalstats(
    const float* __restrict__ part, float* __restrict__ stats) {
  const int w = threadIdx.x >> 6;  // 0..7 = b*4+h
  const int lane = threadIdx.x & 63;
  float s1 = part[((size_t)w * 64 + lane) * 2];
  float s2 = part[((size_t)w * 64 + lane) * 2 + 1];
  s1 = wave_sum(s1);
  s2 = wave_sum(s2);
  if (lane == 0) {
    const float inv = 1.0f / (HD * PP);
    const float mu = s1 * inv;
    const float var = s2 * inv - mu * mu;
    stats[w * 2] = mu;
    stats[w * 2 + 1] = rsqrtf(var + 1e-5f);
  }
}

// ---- final MFMA GEMM: out = sum_g rs_g*(Wog_g @ Ob_g) + obias + x ----
__global__ __launch_bounds__(256) void k_mfma_out(
    const u16t* __restrict__ Wog, const u16t* __restrict__ Obc,
    const float* __restrict__ stats, const float* __restrict__ Rg,
    const float* __restrict__ Cg, const float* __restrict__ x,
    float* __restrict__ outp) {
  const int p0 = blockIdx.x * 64;
  const int ob = blockIdx.y * 64;
  const int b = blockIdx.z;
  const int l = threadIdx.x & 63, w = threadIdx.x >> 6;
  const int lm = l & 15, lk = l >> 4;
  f32x4 acc[4][4] = {};  // [g][j]
  const u16t* Ab = Wog + (ob + w * 16 + lm) * 8;
  const u16t* Bb = Obc + ((size_t)b * 32) * PP * 8 + ((size_t)p0 + lm) * 8;
#pragma unroll
  for (int c0 = 0; c0 < CDIM; c0 += 32) {
    const int g = c0 >> 6;
    const int ch = (c0 >> 3) + lk;
    const bf16x8 af = *(const bf16x8*)(Ab + (size_t)ch * CDIM * 8);
#pragma unroll
    for (int j = 0; j < 4; ++j) {
      const bf16x8 bf = *(const bf16x8*)(Bb + ((size_t)ch * PP + j * 16) * 8);
      acc[g][j] =
          __builtin_amdgcn_mfma_f32_16x16x32_bf16(af, bf, acc[g][j], 0, 0, 0);
    }
  }
  const float mu0 = stats[(b * 4 + 0) * 2], rs0 = stats[(b * 4 + 0) * 2 + 1];
  const float mu1 = stats[(b * 4 + 1) * 2], rs1 = stats[(b * 4 + 1) * 2 + 1];
  const float mu2 = stats[(b * 4 + 2) * 2], rs2 = stats[(b * 4 + 2) * 2 + 1];
  const float mu3 = stats[(b * 4 + 3) * 2], rs3 = stats[(b * 4 + 3) * 2 + 1];
  float obias[4];
#pragma unroll
  for (int r = 0; r < 4; ++r) {
    const int o = ob + w * 16 + lk * 4 + r;
    const float4 rg = *(const float4*)&Rg[o * 4];
    obias[r] = Cg[o] - (rs0 * mu0 * rg.x + rs1 * mu1 * rg.y +
                        rs2 * mu2 * rg.z + rs3 * mu3 * rg.w);
  }
#pragma unroll
  for (int j = 0; j < 4; ++j) {
    const int p = p0 + j * 16 + lm;
#pragma unroll
    for (int r = 0; r < 4; ++r) {
      const int o = ob + w * 16 + lk * 4 + r;
      const float v = rs0 * acc[0][j][r] + rs1 * acc[1][j][r] +
                      rs2 * acc[2][j][r] + rs3 * acc[3][j][r];
      const size_t idx = ((size_t)b * CDIM + o) * PP + p;
      outp[idx] = v + obias[r] + x[idx];
    }
  }
}

extern "C" void kernel_launch(void* const* d_in, const int* in_sizes, int n_in,
                              void* d_out, int out_size, void* d_ws,
                              size_t ws_size, hipStream_t stream) {
  const float* x = (const float*)d_in[0];
  const float* Wq = (const float*)d_in[1];
  const float* Wk = (const float*)d_in[2];
  const float* Wv = (const float*)d_in[3];
  const float* Wo = (const float*)d_in[4];
  const float* bo = (const float*)d_in[5];
  const float* dirW = (const float*)d_in[6];
  const float* dirb = (const float*)d_in[7];
  const float* gnw = (const float*)d_in[8];
  const float* gnb = (const float*)d_in[9];
  float* outp = (float*)d_out;

  float* ws = (float*)d_ws;
  float* offs = ws + 512;    // 1024 floats
  float* pavg = ws + 2048;   // 8192
  float* part = ws + 10240;  // 1024
  float* stats = ws + 11264; // 16
  float* Rg = ws + 11520;    // 1024
  float* Cg = ws + 12544;    // 256
  u16t* xb = (u16t*)(ws + 16384);     // 2,097,152 u16 -> ends f32 1,064,960
  u16t* Wa = (u16t*)(ws + 1064960);   // 196,608 u16 -> ends 1,163,264
  u16t* Wog = (u16t*)(ws + 1163264);  // 65,536 u16 -> ends 1,196,032
  u16t* Qc = (u16t*)(ws + 1228800);   // 2,097,152 u16 -> ends 2,277,376
  u16t* Kc = (u16t*)(ws + 2277376);   // -> ends 3,325,952
  u16t* Vc = (u16t*)(ws + 3325952);   // -> ends 4,374,528
  float* lg = ws + 4374528;           // f32 [8][4096][32] -> ends 5,423,104
  u16t* wb = (u16t*)(ws + 5423104);   // bf16 [8][4096][32] -> ends 5,947,392
  u16t* Obc = (u16t*)lg;              // aliases lg (dead after softmax)

  k_prep<<<dim3(16, 32, 2), dim3(256), 0, stream>>>(x, xb, pavg);
  k_dirs<<<dim3(1), dim3(256), 0, stream>>>(pavg, dirW, dirb, offs);
  k_pack_w<<<dim3(32, 3), dim3(256), 0, stream>>>(Wq, Wk, Wv, Wa);
  k_wprep<<<dim3(256), dim3(256), 0, stream>>>(Wo, bo, gnw, gnb, Wog, Rg, Cg);
  k_mfma_qkv<<<dim3(64, 12, 2), dim3(256), 0, stream>>>(Wa, xb, Qc, Kc, Vc);
  k_logits<<<dim3(16, 4, 8), dim3(256), 0, stream>>>(
      (const uint4*)Qc, (const uint4*)Kc, offs, lg);
  k_softmax<<<dim3(128), dim3(256), 0, stream>>>(lg, wb);
  k_pv<<<dim3(16, 4, 8), dim3(256), 0, stream>>>((const uint4*)Vc, wb, offs,
                                                 Obc, part);
  k_finalstats<<<dim3(1), dim3(512), 0, stream>>>(part, stats);
  k_mfma_out<<<dim3(64, 4, 2), dim3(256), 0, stream>>>(Wog, Obc, stats, Rg, Cg,
                                                       x, outp);
}

// Round 7
// 83.592 us; speedup vs baseline: 1.6684x; 1.2148x over previous
//
#include <hip/hip_runtime.h>
#include <math.h>

#define PP 4096
#define CDIM 256
#define NHEADS 4
#define HD 64

typedef unsigned int u32t;
typedef unsigned short u16t;
typedef __attribute__((ext_vector_type(8))) short bf16x8;
typedef __attribute__((ext_vector_type(4))) float f32x4;

__device__ __forceinline__ float wave_sum(float v) {
#pragma unroll
  for (int off = 32; off > 0; off >>= 1) v += __shfl_down(v, off);
  return v;
}

__device__ __forceinline__ float bflo(u32t w) {
  return __uint_as_float(w << 16);
}
__device__ __forceinline__ float bfhi(u32t w) {
  return __uint_as_float(w & 0xffff0000u);
}
__device__ __forceinline__ u32t pack2(float lo, float hi) {
  const u32t a = __float_as_uint(lo), b = __float_as_uint(hi);
  const u32t l = (a + 0x7fffu + ((a >> 16) & 1u)) >> 16;
  const u32t h = (b + 0x7fffu + ((b >> 16) & 1u)) & 0xffff0000u;
  return l | h;
}
__device__ __forceinline__ u16t f2bf(float f) {
  u32t u = __float_as_uint(f);
  u = u + 0x7fffu + ((u >> 16) & 1u);
  return (u16t)(u >> 16);
}

// ---- prep: pack x f32 [b][c][p] -> bf16 chunked [b][c32][p][8] + avg partials
__global__ __launch_bounds__(256) void k_prep(const float* __restrict__ x,
                                              u16t* __restrict__ xb,
                                              float* __restrict__ pavg) {
  const int p = blockIdx.x * 256 + threadIdx.x;
  const int c32 = blockIdx.y;  // 0..31
  const int b = blockIdx.z;
  const float* s = x + ((size_t)b * CDIM + c32 * 8) * PP + p;
  float f[8];
#pragma unroll
  for (int j = 0; j < 8; ++j) f[j] = s[(size_t)j * PP];
  u32t u[4];
#pragma unroll
  for (int jw = 0; jw < 4; ++jw) u[jw] = pack2(f[2 * jw], f[2 * jw + 1]);
  *(uint4*)&xb[(((size_t)b * 32 + c32) * PP + p) * 8] = *(const uint4*)u;
  __shared__ float red[4][8];
  const int lane = threadIdx.x & 63, wid = threadIdx.x >> 6;
#pragma unroll
  for (int j = 0; j < 8; ++j) {
    const float sj = wave_sum(f[j]);
    if (lane == 0) red[wid][j] = sj;
  }
  __syncthreads();
  if (threadIdx.x < 8) {
    const int j = threadIdx.x;
    pavg[(((size_t)b * 32 + c32) * 16 + blockIdx.x) * 8 + j] =
        red[0][j] + red[1][j] + red[2][j] + red[3][j];
  }
}

// ---- dirs: reduce avg partials -> linear -> normalize -> offsets ----
__global__ __launch_bounds__(256) void k_dirs(const float* __restrict__ pavg,
                                              const float* __restrict__ dirW,
                                              const float* __restrict__ dirb,
                                              float* __restrict__ offs) {
  __shared__ float avg_l[2][256];
  __shared__ float dv[2][32];
  const int c = threadIdx.x;
#pragma unroll
  for (int b = 0; b < 2; ++b) {
    float s = 0.f;
    for (int pb = 0; pb < 16; ++pb)
      s += pavg[(((size_t)b * 32 + (c >> 3)) * 16 + pb) * 8 + (c & 7)];
    avg_l[b][c] = s * (1.0f / PP);
  }
  __syncthreads();
  if (threadIdx.x < 64) {
    const int b = threadIdx.x >> 5, row = threadIdx.x & 31;
    const float* w = dirW + row * CDIM;
    float s = dirb[row];
    for (int cc = 0; cc < CDIM; ++cc) s = fmaf(avg_l[b][cc], w[cc], s);
    dv[b][row] = s;
  }
  __syncthreads();
  if (threadIdx.x < 32) {
    const int b = threadIdx.x >> 4, hs = threadIdx.x & 15;
    float vx = dv[b][hs * 2], vy = dv[b][hs * 2 + 1];
    const float n = fmaxf(sqrtf(vx * vx + vy * vy), 1e-6f);
    vx /= n;
    vy /= n;
#pragma unroll
    for (int m = 0; m < 8; ++m) {
      const float t = -0.5f + m * (1.0f / 7.0f);
      const int o = ((b * 16 + hs) * 8 + m) * 2;
      offs[o] = vx * t;
      offs[o + 1] = vy * t;
    }
  }
}

// ---- wpack: blocks 0..95 pack Wq/Wk/Wv -> Wa; blocks 96..351 do wprep ----
__global__ __launch_bounds__(256) void k_wpack(
    const float* __restrict__ Wq, const float* __restrict__ Wk,
    const float* __restrict__ Wv, const float* __restrict__ Wo,
    const float* __restrict__ bo, const float* __restrict__ gnw,
    const float* __restrict__ gnb, u16t* __restrict__ Wa,
    u16t* __restrict__ Wog, float* __restrict__ Rg, float* __restrict__ Cg) {
  if (blockIdx.x < 96) {
    const int c32 = blockIdx.x & 31;
    const int m = blockIdx.x >> 5;  // 0..2
    const int o = threadIdx.x;
    const float* W = (m == 0 ? Wq : (m == 1 ? Wk : Wv));
    const float4 a = *(const float4*)&W[o * CDIM + c32 * 8];
    const float4 bq = *(const float4*)&W[o * CDIM + c32 * 8 + 4];
    u32t u[4];
    u[0] = pack2(a.x, a.y);
    u[1] = pack2(a.z, a.w);
    u[2] = pack2(bq.x, bq.y);
    u[3] = pack2(bq.z, bq.w);
    *(uint4*)&Wa[(((size_t)m * 32 + c32) * CDIM + o) * 8] = *(const uint4*)u;
  } else {
    const int o = blockIdx.x - 96;  // 0..255
    const int c = threadIdx.x;      // 0..255 ; wave = GN group
    const float wv = Wo[o * CDIM + c];
    const float wg = wv * gnw[c];
    Wog[(((size_t)(c >> 3)) * CDIM + o) * 8 + (c & 7)] = f2bf(wg);
    const float rsum = wave_sum(wg);
    const float csum = wave_sum(wv * gnb[c]);
    __shared__ float redc[4];
    const int lane = c & 63, g = c >> 6;
    if (lane == 0) {
      Rg[o * 4 + g] = rsum;
      redc[g] = csum;
    }
    __syncthreads();
    if (threadIdx.x == 0)
      Cg[o] = bo[o] + redc[0] + redc[1] + redc[2] + redc[3];
  }
}

// ---- fused QKV MFMA GEMM; coalesced chunk-uint4 epilogue via shfl ----
__global__ __launch_bounds__(256) void k_mfma_qkv(const u16t* __restrict__ Wa,
                                                  const u16t* __restrict__ xb,
                                                  u16t* __restrict__ Qc,
                                                  u16t* __restrict__ Kc,
                                                  u16t* __restrict__ Vc) {
  const int p0 = blockIdx.x * 64;
  const int ot = blockIdx.y;     // 0..11
  const int m = ot >> 2;         // 0=Q,1=K,2=V
  const int ob = (ot & 3) * 64;  // o base within matrix
  const int b = blockIdx.z;
  const int l = threadIdx.x & 63, w = threadIdx.x >> 6;
  const int lm = l & 15, lk = l >> 4;
  f32x4 acc[4] = {};
  const u16t* Ab = Wa + ((size_t)m * 32) * CDIM * 8 + (ob + w * 16 + lm) * 8;
  const u16t* Bb = xb + ((size_t)b * 32) * PP * 8 + ((size_t)p0 + lm) * 8;
  for (int c0 = 0; c0 < CDIM; c0 += 32) {
    const int ch = (c0 >> 3) + lk;
    const bf16x8 af = *(const bf16x8*)(Ab + (size_t)ch * CDIM * 8);
#pragma unroll
    for (int j = 0; j < 4; ++j) {
      const bf16x8 bf = *(const bf16x8*)(Bb + ((size_t)ch * PP + j * 16) * 8);
      acc[j] = __builtin_amdgcn_mfma_f32_16x16x32_bf16(af, bf, acc[j], 0, 0, 0);
    }
  }
  u16t* dst = (m == 0 ? Qc : (m == 1 ? Kc : Vc));
  const int c32i = (ob >> 3) + w * 2 + (lk >> 1);
#pragma unroll
  for (int j = 0; j < 4; ++j) {
    const u32t lo = pack2(acc[j][0], acc[j][1]);
    const u32t hi = pack2(acc[j][2], acc[j][3]);
    const u32t plo = __shfl_xor(lo, 16);
    const u32t phi = __shfl_xor(hi, 16);
    if ((l & 16) == 0) {
      uint4 v;
      v.x = lo;
      v.y = hi;
      v.z = plo;
      v.w = phi;
      *(uint4*)&dst[(((size_t)b * 32 + c32i) * PP + p0 + j * 16 + lm) * 8] = v;
    }
  }
}

// ---------------- bilinear sample setup ----------------
struct Samp {
  int i00, i01, i10, i11;
  float w00, w01, w10, w11;
};
__device__ __forceinline__ Samp samp(int xi, int yi, float dxn, float dyn) {
  float gx = fminf(fmaxf(-1.0f + xi * (2.0f / 63.0f) + dxn, -1.0f), 1.0f);
  float gy = fminf(fmaxf(-1.0f + yi * (2.0f / 63.0f) + dyn, -1.0f), 1.0f);
  const float px = (gx + 1.0f) * 31.5f;
  const float py = (gy + 1.0f) * 31.5f;
  const float x0f = floorf(px), y0f = floorf(py);
  const float fx = px - x0f, fy = py - y0f;
  int x0 = (int)x0f;
  x0 = x0 < 0 ? 0 : (x0 > 63 ? 63 : x0);
  int y0 = (int)y0f;
  y0 = y0 < 0 ? 0 : (y0 > 63 ? 63 : y0);
  const int x1 = x0 + 1 > 63 ? 63 : x0 + 1;
  const int y1 = y0 + 1 > 63 ? 63 : y0 + 1;
  Samp sp;
  sp.i00 = y0 * 64 + x0;
  sp.i01 = y0 * 64 + x1;
  sp.i10 = y1 * 64 + x0;
  sp.i11 = y1 * 64 + x1;
  const float ifx = 1.0f - fx, ify = 1.0f - fy;
  sp.w00 = ifx * ify;
  sp.w01 = fx * ify;
  sp.w10 = ifx * fy;
  sp.w11 = fx * fy;
  return sp;
}

__device__ __forceinline__ float dot8(const float* q, uint4 v) {
  float a = q[0] * bflo(v.x);
  a = fmaf(q[1], bfhi(v.x), a);
  a = fmaf(q[2], bflo(v.y), a);
  a = fmaf(q[3], bfhi(v.y), a);
  a = fmaf(q[4], bflo(v.z), a);
  a = fmaf(q[5], bfhi(v.z), a);
  a = fmaf(q[6], bflo(v.w), a);
  a = fmaf(q[7], bfhi(v.w), a);
  return a;
}

__device__ __forceinline__ void acc8(float* a, uint4 v, float w) {
  a[0] = fmaf(w, bflo(v.x), a[0]);
  a[1] = fmaf(w, bfhi(v.x), a[1]);
  a[2] = fmaf(w, bflo(v.y), a[2]);
  a[3] = fmaf(w, bfhi(v.y), a[3]);
  a[4] = fmaf(w, bflo(v.z), a[4]);
  a[5] = fmaf(w, bfhi(v.z), a[5]);
  a[6] = fmaf(w, bflo(v.w), a[6]);
  a[7] = fmaf(w, bfhi(v.w), a[7]);
}

// ---- fused attention: logits + softmax + PV. 4 lanes per pixel (d-quarter).
// block 256 = 4 waves x (16 p x 4 quarters); grid (64 pblocks, 8 bh)
__global__ __launch_bounds__(256) void k_attn(const uint4* __restrict__ Qc,
                                              const uint4* __restrict__ Kc,
                                              const uint4* __restrict__ Vc,
                                              const float* __restrict__ offs,
                                              u16t* __restrict__ Obc,
                                              float* __restrict__ part) {
  __shared__ float lgs[32][64];  // [k][p-local]
  __shared__ float offl[64];
  __shared__ float r1[4], r2[4];
  const int tid = threadIdx.x;
  const int lane = tid & 63, wv = tid >> 6;
  const int p4 = lane & 15;          // p within wave
  const int qt = lane >> 4;          // d-quarter 0..3
  const int pl = wv * 16 + p4;       // p-local 0..63
  const int p = blockIdx.x * 64 + pl;
  const int bh = blockIdx.y;
  const int b = bh >> 2, h = bh & 3;
  if (tid < 64) offl[tid] = offs[(b * 16 + h * 4) * 16 + tid];
  __syncthreads();
  // Q: my 2 chunks (16 d)
  float q[16];
  {
    const uint4* Qp = Qc + ((size_t)b * 32 + h * 8 + qt * 2) * PP + p;
#pragma unroll
    for (int cc = 0; cc < 2; ++cc) {
      const uint4 v = Qp[(size_t)cc * PP];
      q[cc * 8 + 0] = bflo(v.x);
      q[cc * 8 + 1] = bfhi(v.x);
      q[cc * 8 + 2] = bflo(v.y);
      q[cc * 8 + 3] = bfhi(v.y);
      q[cc * 8 + 4] = bflo(v.z);
      q[cc * 8 + 5] = bfhi(v.z);
      q[cc * 8 + 6] = bflo(v.w);
      q[cc * 8 + 7] = bfhi(v.w);
    }
  }
  const int xi = p & 63, yi = p >> 6;
  const uint4* Kb0 = Kc + ((size_t)b * 32 + h * 8 + qt * 2) * PP;
  // phase 1: logits
#pragma unroll 2
  for (int k = 0; k < 32; ++k) {
    const Samp sp = samp(xi, yi, offl[k * 2], offl[k * 2 + 1]);
    float a00 = 0.f, a01 = 0.f, a10 = 0.f, a11 = 0.f;
#pragma unroll
    for (int cc = 0; cc < 2; ++cc) {
      const uint4* base = Kb0 + (size_t)cc * PP;
      const uint4 v00 = base[sp.i00];
      const uint4 v01 = base[sp.i01];
      const uint4 v10 = base[sp.i10];
      const uint4 v11 = base[sp.i11];
      const float* qq = q + cc * 8;
      a00 += dot8(qq, v00);
      a01 += dot8(qq, v01);
      a10 += dot8(qq, v10);
      a11 += dot8(qq, v11);
    }
    float lgv = sp.w00 * a00 + sp.w01 * a01 + sp.w10 * a10 + sp.w11 * a11;
    lgv += __shfl_xor(lgv, 16);
    lgv += __shfl_xor(lgv, 32);
    if (qt == 0) lgs[k][pl] = lgv * 0.125f;  // SCALE
  }
  __syncthreads();
  // softmax (redundant across quarters; qt==0 writes weights back)
  {
    float v[32];
#pragma unroll
    for (int k = 0; k < 32; ++k) v[k] = lgs[k][pl];
    float mx = -1e30f;
#pragma unroll
    for (int k = 0; k < 32; ++k) mx = fmaxf(mx, v[k]);
    float sum = 0.f;
#pragma unroll
    for (int k = 0; k < 32; ++k) {
      v[k] = __expf(v[k] - mx);
      sum += v[k];
    }
    const float inv = 1.0f / sum;
    if (qt == 0) {
#pragma unroll
      for (int k = 0; k < 32; ++k) lgs[k][pl] = v[k] * inv;
    }
  }
  __syncthreads();
  // phase 2: PV over my 16 d
  float acc[16] = {};
  const uint4* Vb0 = Vc + ((size_t)b * 32 + h * 8 + qt * 2) * PP;
#pragma unroll 2
  for (int k = 0; k < 32; ++k) {
    const Samp sp = samp(xi, yi, offl[k * 2], offl[k * 2 + 1]);
    const float ww = lgs[k][pl];
    const float w00 = ww * sp.w00, w01 = ww * sp.w01;
    const float w10 = ww * sp.w10, w11 = ww * sp.w11;
#pragma unroll
    for (int cc = 0; cc < 2; ++cc) {
      const uint4* base = Vb0 + (size_t)cc * PP;
      const uint4 v00 = base[sp.i00];
      const uint4 v01 = base[sp.i01];
      const uint4 v10 = base[sp.i10];
      const uint4 v11 = base[sp.i11];
      float* a = acc + cc * 8;
      acc8(a, v00, w00);
      acc8(a, v01, w01);
      acc8(a, v10, w10);
      acc8(a, v11, w11);
    }
  }
  // store Obc (bf16 chunked)
#pragma unroll
  for (int cc = 0; cc < 2; ++cc) {
    const int c32 = h * 8 + qt * 2 + cc;
    u32t u[4];
#pragma unroll
    for (int jw = 0; jw < 4; ++jw)
      u[jw] = pack2(acc[cc * 8 + 2 * jw], acc[cc * 8 + 2 * jw + 1]);
    *(uint4*)&Obc[(((size_t)b * 32 + c32) * PP + p) * 8] = *(const uint4*)u;
  }
  // GN partials: block covers 64 p x 64 d
  float s1 = 0.f, s2 = 0.f;
#pragma unroll
  for (int d = 0; d < 16; ++d) {
    s1 += acc[d];
    s2 += acc[d] * acc[d];
  }
  s1 = wave_sum(s1);
  s2 = wave_sum(s2);
  if (lane == 0) {
    r1[wv] = s1;
    r2[wv] = s2;
  }
  __syncthreads();
  if (tid == 0) {
    const size_t slot = (size_t)bh * 64 + blockIdx.x;
    part[slot * 2] = r1[0] + r1[1] + r1[2] + r1[3];
    part[slot * 2 + 1] = r2[0] + r2[1] + r2[2] + r2[3];
  }
}

// ---- final MFMA GEMM with GN-stats prologue:
//      out = sum_g rs_g*(Wog_g @ Ob_g) + [Cg - sum_g rs_g*mu_g*Rg] + x
__global__ __launch_bounds__(256) void k_mfma_out(
    const u16t* __restrict__ Wog, const u16t* __restrict__ Obc,
    const float* __restrict__ part, const float* __restrict__ Rg,
    const float* __restrict__ Cg, const float* __restrict__ x,
    float* __restrict__ outp) {
  __shared__ float mul[8], rsl[8], sraw[16];
  {
    const int t = threadIdx.x;
    const int bh = t >> 5, idx = t & 31;
    float s1 = part[((size_t)(bh * 64 + idx)) * 2] +
               part[((size_t)(bh * 64 + 32 + idx)) * 2];
    float s2 = part[((size_t)(bh * 64 + idx)) * 2 + 1] +
               part[((size_t)(bh * 64 + 32 + idx)) * 2 + 1];
#pragma unroll
    for (int off = 16; off > 0; off >>= 1) {
      s1 += __shfl_down(s1, off, 32);
      s2 += __shfl_down(s2, off, 32);
    }
    if (idx == 0) {
      sraw[bh * 2] = s1;
      sraw[bh * 2 + 1] = s2;
    }
  }
  __syncthreads();
  if (threadIdx.x < 8) {
    const int t = threadIdx.x;
    const float inv = 1.0f / (HD * PP);
    const float mu = sraw[t * 2] * inv;
    const float var = sraw[t * 2 + 1] * inv - mu * mu;
    mul[t] = mu;
    rsl[t] = rsqrtf(var + 1e-5f);
  }
  __syncthreads();
  const int p0 = blockIdx.x * 64;
  const int ob = blockIdx.y * 64;
  const int b = blockIdx.z;
  const int l = threadIdx.x & 63, w = threadIdx.x >> 6;
  const int lm = l & 15, lk = l >> 4;
  f32x4 acc[4][4] = {};  // [g][j]
  const u16t* Ab = Wog + (ob + w * 16 + lm) * 8;
  const u16t* Bb = Obc + ((size_t)b * 32) * PP * 8 + ((size_t)p0 + lm) * 8;
#pragma unroll
  for (int c0 = 0; c0 < CDIM; c0 += 32) {
    const int g = c0 >> 6;
    const int ch = (c0 >> 3) + lk;
    const bf16x8 af = *(const bf16x8*)(Ab + (size_t)ch * CDIM * 8);
#pragma unroll
    for (int j = 0; j < 4; ++j) {
      const bf16x8 bf = *(const bf16x8*)(Bb + ((size_t)ch * PP + j * 16) * 8);
      acc[g][j] =
          __builtin_amdgcn_mfma_f32_16x16x32_bf16(af, bf, acc[g][j], 0, 0, 0);
    }
  }
  const float mu0 = mul[b * 4 + 0], rs0 = rsl[b * 4 + 0];
  const float mu1 = mul[b * 4 + 1], rs1 = rsl[b * 4 + 1];
  const float mu2 = mul[b * 4 + 2], rs2 = rsl[b * 4 + 2];
  const float mu3 = mul[b * 4 + 3], rs3 = rsl[b * 4 + 3];
  float obias[4];
#pragma unroll
  for (int r = 0; r < 4; ++r) {
    const int o = ob + w * 16 + lk * 4 + r;
    const float4 rg = *(const float4*)&Rg[o * 4];
    obias[r] = Cg[o] - (rs0 * mu0 * rg.x + rs1 * mu1 * rg.y +
                        rs2 * mu2 * rg.z + rs3 * mu3 * rg.w);
  }
#pragma unroll
  for (int j = 0; j < 4; ++j) {
    const int p = p0 + j * 16 + lm;
#pragma unroll
    for (int r = 0; r < 4; ++r) {
      const int o = ob + w * 16 + lk * 4 + r;
      const float v = rs0 * acc[0][j][r] + rs1 * acc[1][j][r] +
                      rs2 * acc[2][j][r] + rs3 * acc[3][j][r];
      const size_t idx = ((size_t)b * CDIM + o) * PP + p;
      outp[idx] = v + obias[r] + x[idx];
    }
  }
}

extern "C" void kernel_launch(void* const* d_in, const int* in_sizes, int n_in,
                              void* d_out, int out_size, void* d_ws,
                              size_t ws_size, hipStream_t stream) {
  const float* x = (const float*)d_in[0];
  const float* Wq = (const float*)d_in[1];
  const float* Wk = (const float*)d_in[2];
  const float* Wv = (const float*)d_in[3];
  const float* Wo = (const float*)d_in[4];
  const float* bo = (const float*)d_in[5];
  const float* dirW = (const float*)d_in[6];
  const float* dirb = (const float*)d_in[7];
  const float* gnw = (const float*)d_in[8];
  const float* gnb = (const float*)d_in[9];
  float* outp = (float*)d_out;

  float* ws = (float*)d_ws;
  float* offs = ws + 512;    // 1024 floats
  float* pavg = ws + 2048;   // 8192
  float* part = ws + 10240;  // 1024 (512 slots x 2)
  float* Rg = ws + 11520;    // 1024
  float* Cg = ws + 12544;    // 256
  u16t* xb = (u16t*)(ws + 16384);     // 2,097,152 u16
  u16t* Wa = (u16t*)(ws + 1064960);   // 196,608 u16
  u16t* Wog = (u16t*)(ws + 1163264);  // 65,536 u16
  u16t* Qc = (u16t*)(ws + 1228800);   // 2,097,152 u16
  u16t* Kc = (u16t*)(ws + 2277376);
  u16t* Vc = (u16t*)(ws + 3325952);
  u16t* Obc = (u16t*)(ws + 4374528);  // 2,097,152 u16

  k_prep<<<dim3(16, 32, 2), dim3(256), 0, stream>>>(x, xb, pavg);
  k_wpack<<<dim3(352), dim3(256), 0, stream>>>(Wq, Wk, Wv, Wo, bo, gnw, gnb,
                                               Wa, Wog, Rg, Cg);
  k_dirs<<<dim3(1), dim3(256), 0, stream>>>(pavg, dirW, dirb, offs);
  k_mfma_qkv<<<dim3(64, 12, 2), dim3(256), 0, stream>>>(Wa, xb, Qc, Kc, Vc);
  k_attn<<<dim3(64, 8), dim3(256), 0, stream>>>(
      (const uint4*)Qc, (const uint4*)Kc, (const uint4*)Vc, offs, Obc, part);
  k_mfma_out<<<dim3(64, 4, 2), dim3(256), 0, stream>>>(Wog, Obc, part, Rg, Cg,
                                                       x, outp);
}